// Round 8
// baseline (129.047 us; speedup 1.0000x reference)
//
#include <hip/hip_runtime.h>
#include <hip/hip_bf16.h>

#define E_ 8
#define B_ 8
#define S_ 2048
#define D_ 512
#define R_ 128
#define M_TOT (B_ * S_)   // 16384

typedef __attribute__((ext_vector_type(8))) short bf16x8;
typedef __attribute__((ext_vector_type(4))) float f32x4;

__device__ __forceinline__ void gload_lds16(void* lds, const void* g) {
  __builtin_amdgcn_global_load_lds(
      (const __attribute__((address_space(1))) void*)g,
      (__attribute__((address_space(3))) void*)lds, 16, 0, 0);
}

// ---------------------------------------------------------------------------
// Fused prep kernel (unchanged from R5):
//   [0,16) rotation recurrence | [16,2064) W tail | [2064,6160) x -> bf16
// ---------------------------------------------------------------------------
#define ROT_B 16
#define WT_B 2048
#define CX_B 4096
__global__ __launch_bounds__(256) void prep_fused(
    const float* __restrict__ x, const float* __restrict__ theta,
    const float* __restrict__ pw, __hip_bfloat16* __restrict__ xb,
    __hip_bfloat16* __restrict__ Wb) {
  int blk = blockIdx.x;
  int t = threadIdx.x;
  if (blk < ROT_B) {
    __shared__ float cs[R_], ss[R_];
    __shared__ float Pch[256][17];
    __shared__ __hip_bfloat16 Wch[256][18];
    int e = blk >> 1;
    int r0 = (blk & 1) * 256;
    if (t < R_) {
      float a = tanhf(theta[e * R_ + t]) * 0.1f;
      cs[t] = cosf(a);
      ss[t] = sinf(a);
    }
    const float* Pe = pw + (size_t)e * D_ * D_;
    __hip_bfloat16* We = Wb + (size_t)e * D_ * D_;
    float u = Pe[(size_t)(r0 + t) * D_];
    __syncthreads();
    for (int c = 0; c < 8; ++c) {
      for (int i = t; i < 256 * 16; i += 256) {
        int row = i >> 4, col = i & 15;
        Pch[row][col] = Pe[(size_t)(r0 + row) * D_ + 1 + 16 * c + col];
      }
      __syncthreads();
#pragma unroll
      for (int kk = 0; kk < 16; ++kk) {
        int k = 16 * c + kk;
        float pj = Pch[t][kk];
        Wch[t][kk] = __float2bfloat16(cs[k] * pj - ss[k] * u);
        u = cs[k] * u + ss[k] * pj;
      }
      __syncthreads();
      for (int i = t; i < 256 * 16; i += 256) {
        int row = i >> 4, col = i & 15;
        We[(size_t)(r0 + row) * D_ + 1 + 16 * c + col] = Wch[row][col];
      }
      __syncthreads();
    }
    We[(size_t)(r0 + t) * D_] = __float2bfloat16(u);
  } else if (blk < ROT_B + WT_B) {
    int g = (blk - ROT_B) * 256 + t;
    int gidx = g & 127;
    if (gidx < 32) return;
    float4 v = ((const float4*)pw)[g];
    union { short4 s; __hip_bfloat16 h[4]; } u;
    u.h[0] = __float2bfloat16(v.x);
    u.h[1] = __float2bfloat16(v.y);
    u.h[2] = __float2bfloat16(v.z);
    u.h[3] = __float2bfloat16(v.w);
    if (gidx > 32) {
      ((short4*)Wb)[g] = u.s;
    } else {
      Wb[(size_t)g * 4 + 1] = u.h[1];
      Wb[(size_t)g * 4 + 2] = u.h[2];
      Wb[(size_t)g * 4 + 3] = u.h[3];
    }
  } else {
    int i = (blk - ROT_B - WT_B) * 256 + t;
#pragma unroll
    for (int rep = 0; rep < 2; ++rep) {
      int idx = i + rep * (CX_B * 256);
      float4 v = ((const float4*)x)[idx];
      union { short4 s; __hip_bfloat16 h[4]; } u;
      u.h[0] = __float2bfloat16(v.x);
      u.h[1] = __float2bfloat16(v.y);
      u.h[2] = __float2bfloat16(v.z);
      u.h[3] = __float2bfloat16(v.w);
      ((short4*)xb)[idx] = u.s;
    }
  }
}

// ---------------------------------------------------------------------------
// GEMM: out[e] = Xb @ Wb[e]^T (NT). 256x256, BK=64, NT=8 tiles, 8 waves.
// 4-phase/tile interleaved schedule: per phase {ds_read next quad's frags ||
// 1 stage unit -> raw s_barrier (+lgkmcnt(0) where reads precede) ->
// setprio(1) 16 MFMA setprio(0)}. vmcnt NEVER drains mid-loop (raw barriers
// only; explicit lgkmcnt drains LDS reads only). 4 half-slot rings.
// Race-safety: a stage aliasing a read-slot is issued only in a phase AFTER
// the lgkmcnt(0)+barrier that drained all reads of that slot.
// T1 XCD swizzle, T2 involutive chunk swizzle c^(row&7), T5 setprio.
// ---------------------------------------------------------------------------
__global__ __launch_bounds__(512, 2) void gemm_xw(
    const __hip_bfloat16* __restrict__ Xb,   // [M_TOT][512]
    const __hip_bfloat16* __restrict__ Wb,   // [E][512][512] rows=o, cols=d
    float* __restrict__ out)                 // [E][M_TOT][512]
{
  constexpr int BK = 64;
  constexpr int KD = D_, ND = D_;
  constexpr int NT = KD / BK;  // 8
  __shared__ __align__(16) __hip_bfloat16 As[4][128 * 64];  // 64 KB
  __shared__ __align__(16) __hip_bfloat16 Bs[4][128 * 64];  // 64 KB

  int bx = blockIdx.x;                 // 1024 blocks
  int swz = (bx & 7) * 128 + (bx >> 3);
  int mt = swz >> 4;          // 0..63
  int e  = (swz >> 1) & 7;    // 0..7
  int nt = swz & 1;           // 0..1

  int tid = threadIdx.x;
  int wave = tid >> 6, lane = tid & 63;
  int lr = lane & 15, lk = lane >> 4;
  int wm = wave >> 2, wn = wave & 3;   // wave-tile 128x64 of C

  const __hip_bfloat16* Ag = Xb + (size_t)(mt * 256) * KD;
  const __hip_bfloat16* Bg = Wb + ((size_t)e * ND + (size_t)nt * 256) * KD;

  // staging: lane -> row lane>>3, chunk (lane&7)^(lane>>3) (involution,
  // within-row 16B permutation -> full per-row coalescing kept)
  int srow = lane >> 3;
  int scol = ((lane & 7) ^ srow) * 8;

  // fragment read chunk terms: phys chunk = (kk*4+lk) ^ (lr&7)
  int axor0 = ((0 * 4 + lk) ^ (lr & 7)) * 8;
  int axor1 = ((1 * 4 + lk) ^ (lr & 7)) * 8;

  f32x4 acc[8][4];
#pragma unroll
  for (int i = 0; i < 8; ++i)
#pragma unroll
    for (int j = 0; j < 4; ++j) acc[i][j] = (f32x4){0.f, 0.f, 0.f, 0.f};

#define STAGE(ARR, GBASE, h, tt)                                             \
  {                                                                          \
    int slot_ = (2 * (tt) + (h)) & 3;                                        \
    _Pragma("unroll") for (int g = 0; g < 2; ++g) {                          \
      gload_lds16(&ARR[slot_][(wave * 16 + g * 8) * 64],                     \
                  (GBASE) + (size_t)((h) * 128 + wave * 16 + g * 8 + srow) * \
                                KD + (tt) * BK + scol);                      \
    }                                                                        \
  }

#define QUAD(AF, BF, mh, nh)                                                 \
  {                                                                          \
    __builtin_amdgcn_s_setprio(1);                                           \
    _Pragma("unroll") for (int m4 = 0; m4 < 4; ++m4)                         \
        _Pragma("unroll") for (int n2 = 0; n2 < 2; ++n2)                     \
            _Pragma("unroll") for (int kk = 0; kk < 2; ++kk)                 \
                acc[(mh)*4 + m4][(nh)*2 + n2] =                              \
                    __builtin_amdgcn_mfma_f32_16x16x32_bf16(                 \
                        AF[m4][kk], BF[n2][kk],                              \
                        acc[(mh)*4 + m4][(nh)*2 + n2], 0, 0, 0);             \
    __builtin_amdgcn_s_setprio(0);                                           \
  }

#define LGKM0                                                                \
  asm volatile("s_waitcnt lgkmcnt(0)" ::: "memory");                         \
  __builtin_amdgcn_sched_barrier(0);

  // prologue: tile0 complete + B0,A0,A1 of tile1  (unit order fixes vmcnt)
  STAGE(As, Ag, 0, 0); STAGE(As, Ag, 1, 0);
  STAGE(Bs, Bg, 0, 0); STAGE(Bs, Bg, 1, 0);
  STAGE(Bs, Bg, 0, 1);
  STAGE(As, Ag, 0, 1); STAGE(As, Ag, 1, 1);

#pragma unroll
  for (int t = 0; t < NT; ++t) {
    // tile t resident once <=6 newer loads (3 units) remain in flight
    if (t < NT - 1) {
      asm volatile("s_waitcnt vmcnt(6)" ::: "memory");
    } else {
      asm volatile("s_waitcnt vmcnt(0)" ::: "memory");
    }
    __builtin_amdgcn_s_barrier();

    const __hip_bfloat16* Asl = As[(2 * t + wm) & 3];
    const __hip_bfloat16* Bsl = Bs[(2 * t + (wn >> 1)) & 3];

    // ---- p0: read af-lo + bfr-lo | stage B1(t+1) (slot never read here) ---
    bf16x8 af_lo[4][2], bfr_lo[2][2];
#pragma unroll
    for (int mi = 0; mi < 4; ++mi) {
      int rb = (mi * 16 + lr) * 64;
      af_lo[mi][0] = *(const bf16x8*)&Asl[rb + axor0];
      af_lo[mi][1] = *(const bf16x8*)&Asl[rb + axor1];
    }
#pragma unroll
    for (int ni = 0; ni < 2; ++ni) {
      int rb = ((wn & 1) * 64 + ni * 16 + lr) * 64;
      bfr_lo[ni][0] = *(const bf16x8*)&Bsl[rb + axor0];
      bfr_lo[ni][1] = *(const bf16x8*)&Bsl[rb + axor1];
    }
    if (t + 1 < NT) STAGE(Bs, Bg, 1, t + 1);
    LGKM0;
    __builtin_amdgcn_s_barrier();
    QUAD(af_lo, bfr_lo, 0, 0);

    // ---- p1: read bfr-hi ----
    bf16x8 bfr_hi[2][2];
#pragma unroll
    for (int ni = 0; ni < 2; ++ni) {
      int rb = ((wn & 1) * 64 + (2 + ni) * 16 + lr) * 64;
      bfr_hi[ni][0] = *(const bf16x8*)&Bsl[rb + axor0];
      bfr_hi[ni][1] = *(const bf16x8*)&Bsl[rb + axor1];
    }
    LGKM0;                 // all B reads of tile t now drained (all waves at
    __builtin_amdgcn_s_barrier();  // this barrier) -> B slots reusable next phase
    QUAD(af_lo, bfr_hi, 0, 1);

    // ---- p2: read af-hi | stage B0(t+2) (B reads drained at p1) ----
    bf16x8 af_hi[4][2];
#pragma unroll
    for (int mi = 0; mi < 4; ++mi) {
      int rb = ((4 + mi) * 16 + lr) * 64;
      af_hi[mi][0] = *(const bf16x8*)&Asl[rb + axor0];
      af_hi[mi][1] = *(const bf16x8*)&Asl[rb + axor1];
    }
    if (t + 2 < NT) STAGE(Bs, Bg, 0, t + 2);
    LGKM0;                 // all A reads of tile t drained -> A slots reusable
    __builtin_amdgcn_s_barrier();
    QUAD(af_hi, bfr_lo, 1, 0);

    // ---- p3: stage A0,A1(t+2) (A reads drained at p2) ----
    if (t + 2 < NT) { STAGE(As, Ag, 0, t + 2); STAGE(As, Ag, 1, t + 2); }
    __builtin_amdgcn_s_barrier();
    QUAD(af_hi, bfr_hi, 1, 1);
  }
#undef STAGE
#undef QUAD
#undef LGKM0

  // epilogue: C/D layout col = lane&15, row = (lane>>4)*4 + reg  [m89]
  size_t obase = (size_t)e * M_TOT * ND;
  int row0 = mt * 256 + wm * 128;
  int col0 = nt * 256 + wn * 64;
#pragma unroll
  for (int mi = 0; mi < 8; ++mi)
#pragma unroll
    for (int ni = 0; ni < 4; ++ni) {
      int r0 = row0 + mi * 16 + lk * 4;
      int c = col0 + ni * 16 + lr;
      float* op = out + obase + (size_t)r0 * ND + c;
#pragma unroll
      for (int q = 0; q < 4; ++q) op[(size_t)q * ND] = acc[mi][ni][q];
    }
}

extern "C" void kernel_launch(void* const* d_in, const int* in_sizes, int n_in,
                              void* d_out, int out_size, void* d_ws, size_t ws_size,
                              hipStream_t stream) {
  const float* x = (const float*)d_in[0];        // [B][S][D] f32
  const float* theta = (const float*)d_in[1];    // [E][R] f32
  const float* proj_w = (const float*)d_in[2];   // [E][D][D] f32
  float* out = (float*)d_out;                    // [E][B][S][D] f32

  __hip_bfloat16* xb = (__hip_bfloat16*)d_ws;                          // 16 MB
  __hip_bfloat16* Wb = (__hip_bfloat16*)((char*)d_ws +
                        (size_t)M_TOT * D_ * sizeof(__hip_bfloat16));  // 4 MB

  hipLaunchKernelGGL(prep_fused, dim3(ROT_B + WT_B + CX_B), dim3(256), 0,
                     stream, x, theta, proj_w, xb, Wb);
  hipLaunchKernelGGL(gemm_xw, dim3(E_ * (M_TOT / 256) * (D_ / 256)), dim3(512),
                     0, stream, xb, Wb, out);
}